// Round 15
// baseline (297.755 us; speedup 1.0000x reference)
//
#include <hip/hip_runtime.h>

// Linear(int8-weight, block-sparse) -> quantize -> dequantize, as one fp16 MFMA GEMM.
// out[n,o] = dq(q( (x @ (w_q*mask)^T) * w_scale + bias ))
// N=8192 tokens, O=4096, K=4096.
//
// Numerics: w_q*mask integers in [-127,127] exact in fp16 (validated absmax 0.0625).
//
// GEMM round 15: 4 WAVES x 128x128 WAVE-TILE (was 8 x 128x64).
// Rationale: per-SIMD MFMA cost is 19.4 cyc (m06 2075 TF / 1024 SIMD), so
// the 8-wave config's per-phase MFMA window (2 waves x 16 x 19.4 = 621cyc)
// merely EQUALED the per-CU LDS demand (576+ cyc) -> LDS/MFMA parity ->
// every skew stalls; 8 schedule variants all pinned 238-246us. The wave
// tile sets reads:MFMA = 8(Mw+Nw)/(Mw*Nw): 128x64 -> 0.375, 128x128 ->
// 0.25. At 4 waves x 128x128: per-phase LDS ~510cyc < MFMA 620cyc ->
// MFMA-bound, 18% slack. MFMA floor = 132us (vs 238 now).
// 1 wave/SIMD: acc[8][8]=256 regs + frags/addr ~420 < 512 budget
// (__launch_bounds__(256,1)); 64 independent accumulators give the ILP.
//
// Schedule = r12's verbatim, n-width doubled (counts x2 for 256 threads):
//   P1: rd a47.kh0[4]+b1v(0-3)[4]; stg B_k0(s+2)->sb[4]; MFMA m03.kh0x8n; LGKM0; BAR
//   P2: rd a03.kh1[4]+b1v(4-7)[4]; stg A_k0(s+2)->sb[4]; MFMA m47.kh0; LGKM0; VMCNT(8|0); BAR
//   P3: rd a47.kh1[4]+b0v'(0-3)[4]; stg B_k1(s+2)->sb[4]; MFMA m03.kh1; LGKM0; BAR
//   P4: rd a03.kh0'[4]+b0v'(4-7)[4]; stg A_k1(s+2)->sb[4]; MFMA m47.kh1; LGKM0; BAR
// vmcnt: end-P2(s) outstanding = P1(s)+P2(s) stages = 8 -> VMCNT(8) forces
// all of buf(s+1) (staged P1..P4(s-1), flight 2-5 phases). Tail s>=NT-2: 0.
// WAR (r12-verified logic): each pane staged >=1 barrier after its last
// reader's LGKM0 drain. T2 granule-XOR swizzle unchanged (0 conflicts).

#define M_TOK 8192
#define O_FEAT 4096
#define K_FEAT 4096

#define BM 256
#define BN 256
#define BK 64
#define NT (K_FEAT / BK)   // 64 K-tiles

// LDS element strides for smem[2][2][2][BM*32]: buf=32768, mat=16384, kh=8192
#define S_BUF 32768
#define S_MAT 16384
#define S_KH  8192

using f16x8 = __attribute__((ext_vector_type(8))) _Float16;
using f32x4 = __attribute__((ext_vector_type(4))) float;

#define BAR()    asm volatile("s_barrier" ::: "memory")
#define LGKM0()  asm volatile("s_waitcnt lgkmcnt(0)" ::: "memory")
#define VMCNT(n) asm volatile("s_waitcnt vmcnt(" #n ")" ::: "memory")
#define SB0()    __builtin_amdgcn_sched_barrier(0)
#define MFMA16(a, b, c) __builtin_amdgcn_mfma_f32_16x16x32_f16((a), (b), (c), 0, 0, 0)

#define NXBLK (M_TOK * K_FEAT / 8 / 256)   // 16384 x-blocks

// ------------- fused fp32->fp16 conversion (x) + mask-fuse (w) ---------
__global__ __launch_bounds__(256) void cvt_kernel(const float* __restrict__ x,
                                                  const float* __restrict__ wq,
                                                  const int* __restrict__ mask,
                                                  _Float16* __restrict__ xf,
                                                  _Float16* __restrict__ wf) {
    const int b = blockIdx.x;
    if (b < NXBLK) {
        size_t i = ((size_t)b * 256 + threadIdx.x) * 8;
        float4 v0 = *reinterpret_cast<const float4*>(x + i);
        float4 v1 = *reinterpret_cast<const float4*>(x + i + 4);
        f16x8 h;
        h[0] = (_Float16)v0.x; h[1] = (_Float16)v0.y;
        h[2] = (_Float16)v0.z; h[3] = (_Float16)v0.w;
        h[4] = (_Float16)v1.x; h[5] = (_Float16)v1.y;
        h[6] = (_Float16)v1.z; h[7] = (_Float16)v1.w;
        *reinterpret_cast<f16x8*>(xf + i) = h;
    } else {
        size_t i = ((size_t)(b - NXBLK) * 256 + threadIdx.x) * 8;
        float4 v0 = *reinterpret_cast<const float4*>(wq + i);
        float4 v1 = *reinterpret_cast<const float4*>(wq + i + 4);
        int2 mv = *reinterpret_cast<const int2*>(mask + i / 4);
        float m0 = mv.x ? 1.0f : 0.0f;
        float m1 = mv.y ? 1.0f : 0.0f;
        f16x8 h;
        h[0] = (_Float16)(v0.x * m0); h[1] = (_Float16)(v0.y * m0);
        h[2] = (_Float16)(v0.z * m0); h[3] = (_Float16)(v0.w * m0);
        h[4] = (_Float16)(v1.x * m1); h[5] = (_Float16)(v1.y * m1);
        h[6] = (_Float16)(v1.z * m1); h[7] = (_Float16)(v1.w * m1);
        *reinterpret_cast<f16x8*>(wf + i) = h;
    }
}

// ---------------- 256x256, 4-wave 128x128, 4-phase fp16 MFMA GEMM -------
// A [8192][4096] f16 row-major, B [4096][4096] f16 row-major (B^T GEMM).
// Swizzle: 16B granule kq -> kq ^ ((row>>1)&3); linear LDS dest +
// inverse-permuted global src (global_load_lds), same XOR on ds_read.
__global__ __launch_bounds__(256, 1) void gemm_kernel(const _Float16* __restrict__ A,
                                                      const _Float16* __restrict__ B,
                                                      const float* __restrict__ bias,
                                                      const float* __restrict__ wsp,
                                                      const float* __restrict__ osp,
                                                      float* __restrict__ C) {
    __shared__ __align__(16) _Float16 smem[2][2][2][BM * 32];
    _Float16* sm = &smem[0][0][0][0];

    const int tid  = threadIdx.x;
    const int lane = tid & 63;
    const int w    = tid >> 6;      // 0..3
    const int wm   = w >> 1;        // 0..1  (M half)
    const int wn   = w & 1;         // 0..1  (N half)
    const int lr   = lane & 15;     // fragment row/col
    const int kq   = lane >> 4;     // 0..3  k-granule

    const int bm = blockIdx.x >> 4; // 32 M-tiles
    const int bn = blockIdx.x & 15; // 16 N-tiles

    // ---- staging geometry: 256 threads, 4 gloads per 16KiB pane ----
    const int sr0  = tid >> 2;                              // rows 0..63 per issue
    const int csrc = ((tid & 3) ^ ((tid >> 3) & 3)) * 8;    // inverse-swizzled src granule
    const size_t J64 = (size_t)64 * K_FEAT;                 // +64 rows

    const _Float16* pA0 = A + (size_t)(bm * BM + sr0) * K_FEAT + csrc;  // A kh0
    const _Float16* pA1 = pA0 + 32;                                      // A kh1
    const _Float16* pB0 = B + (size_t)(bn * BN + sr0) * K_FEAT + csrc;  // B kh0
    const _Float16* pB1 = pB0 + 32;                                      // B kh1

    const int dstT = tid * 8;   // LDS dst elem offset within a pane (issue j: +j*2048)

    auto stg = [&](const _Float16* src, const _Float16* panep) {
#pragma unroll
        for (int j = 0; j < 4; ++j)
            __builtin_amdgcn_global_load_lds(
                (const __attribute__((address_space(1))) void*)(const void*)(src + j * J64),
                (__attribute__((address_space(3))) void*)(void*)(_Float16*)(uintptr_t)(panep + dstT + j * 2048),
                16, 0, 0);
    };

    // ---- fragment read offsets (hoisted, swizzled) ----
    int offA[4], offB[8];
#pragma unroll
    for (int m = 0; m < 4; ++m) {
        const int r = wm * 128 + m * 16 + lr;
        offA[m] = r * 32 + ((kq ^ ((r >> 1) & 3)) << 3);
    }
#pragma unroll
    for (int n = 0; n < 8; ++n) {
        const int r = wn * 128 + n * 16 + lr;
        offB[n] = r * 32 + ((kq ^ ((r >> 1) & 3)) << 3);
    }
    auto rd = [&](const _Float16* sbuf, int off, int immE) -> f16x8 {
        return *reinterpret_cast<const f16x8*>(sbuf + off + immE);  // immE folds into ds offset
    };

    f32x4 acc[8][8] = {};
    f16x8 a0[4], a1[4], b0v[8], b1v[8];

    // ---- prologue: stage tile0->buf0, tile1->buf1 (32 loads) ----
    stg(pA0, sm);                 stg(pB0, sm + S_MAT);
    stg(pA1, sm + S_KH);          stg(pB1, sm + S_MAT + S_KH);
    pA0 += BK; pA1 += BK; pB0 += BK; pB1 += BK;   // -> tile 1
    stg(pA0, sm + S_BUF);         stg(pB0, sm + S_BUF + S_MAT);
    stg(pA1, sm + S_BUF + S_KH);  stg(pB1, sm + S_BUF + S_MAT + S_KH);
    pA0 += BK; pA1 += BK; pB0 += BK; pB1 += BK;   // -> tile 2 (first staged in-loop)
    VMCNT(16);   // tile0 landed; tile1 in flight
    BAR();
    // prime P1(0) operands from buf0, then drain+barrier (P1/P2(0) stages
    // overwrite buf0.B_k0 / buf0.A_k0 -- the panes these reads touch)
#pragma unroll
    for (int m = 0; m < 4; ++m) a0[m] = rd(sm, offA[m], 0);
#pragma unroll
    for (int n = 0; n < 8; ++n) b0v[n] = rd(sm, offB[n], S_MAT);
    LGKM0();
    BAR();

    for (int s = 0; s < NT; ++s) {
        const _Float16* sb = sm + ((s & 1) ? S_BUF : 0);   // current buf
        const _Float16* sn = sm + ((s & 1) ? 0 : S_BUF);   // next buf
        const bool more = (s + 1 < NT);
        const bool stg_ok = (s + 2 < NT);

        // ---- P1: rd a47_k0[4] + b1v0-3[4]; stg B_k0(s+2)->sb; MFMA m03.kh0 ----
#pragma unroll
        for (int m = 0; m < 4; ++m) a1[m] = rd(sb, offA[m], 2048);
#pragma unroll
        for (int n = 0; n < 4; ++n) b1v[n] = rd(sb, offB[n], S_MAT + S_KH);
        if (stg_ok) stg(pB0, sb + S_MAT);
        SB0();
        __builtin_amdgcn_s_setprio(1);
#pragma unroll
        for (int m = 0; m < 4; ++m)
#pragma unroll
            for (int n = 0; n < 8; ++n)
                acc[m][n] = MFMA16(a0[m], b0v[n], acc[m][n]);
        __builtin_amdgcn_s_setprio(0);
        SB0(); LGKM0();   // own reads ran under the MFMA; drain for WAR
        BAR();

        // ---- P2: rd a03_k1[4] + b1v4-7[4]; stg A_k0(s+2)->sb; MFMA m47.kh0; publish ----
#pragma unroll
        for (int m = 0; m < 4; ++m) a0[m] = rd(sb, offA[m], S_KH);
#pragma unroll
        for (int n = 4; n < 8; ++n) b1v[n] = rd(sb, offB[n], S_MAT + S_KH);
        if (stg_ok) stg(pA0, sb);
        SB0();
        __builtin_amdgcn_s_setprio(1);
#pragma unroll
        for (int m = 0; m < 4; ++m)
#pragma unroll
            for (int n = 0; n < 8; ++n)
                acc[4 + m][n] = MFMA16(a1[m], b0v[n], acc[4 + m][n]);
        __builtin_amdgcn_s_setprio(0);
        SB0(); LGKM0();
        // publish buf(s+1): all stages through P4(s-1) landed; P1,P2(s)
        // stages (8 loads) may stay in flight. Tail: drain all.
        if (s >= NT - 2) { VMCNT(0); } else { VMCNT(8); }
        BAR();

        // ---- P3: rd a47_k1[4] + b0v0-3'(sn)[4]; stg B_k1(s+2)->sb; MFMA m03.kh1 ----
#pragma unroll
        for (int m = 0; m < 4; ++m) a1[m] = rd(sb, offA[m], S_KH + 2048);
        if (more) {
#pragma unroll
            for (int n = 0; n < 4; ++n) b0v[n] = rd(sn, offB[n], S_MAT);
        }
        if (stg_ok) stg(pB1, sb + S_MAT + S_KH);
        SB0();
        __builtin_amdgcn_s_setprio(1);
#pragma unroll
        for (int m = 0; m < 4; ++m)
#pragma unroll
            for (int n = 0; n < 8; ++n)
                acc[m][n] = MFMA16(a0[m], b1v[n], acc[m][n]);
        __builtin_amdgcn_s_setprio(0);
        SB0(); LGKM0();
        BAR();

        // ---- P4: rd a03_k0'(sn)[4] + b0v4-7'(sn)[4]; stg A_k1(s+2)->sb; MFMA m47.kh1 ----
        if (more) {
#pragma unroll
            for (int m = 0; m < 4; ++m) a0[m] = rd(sn, offA[m], 0);
#pragma unroll
            for (int n = 4; n < 8; ++n) b0v[n] = rd(sn, offB[n], S_MAT);
        }
        if (stg_ok) stg(pA1, sb + S_KH);
        SB0();
        __builtin_amdgcn_s_setprio(1);
#pragma unroll
        for (int m = 0; m < 4; ++m)
#pragma unroll
            for (int n = 0; n < 8; ++n)
                acc[4 + m][n] = MFMA16(a1[m], b1v[n], acc[4 + m][n]);
        __builtin_amdgcn_s_setprio(0);
        SB0(); LGKM0();
        BAR();

        pA0 += BK; pA1 += BK; pB0 += BK; pB1 += BK;
    }

    // ---------------- fused epilogue: scale + bias + quant + dequant ----
    const float wscale = wsp[0];
    const float oscale = osp[0];
    const int row0 = bm * BM + wm * 128;
    const int col0 = bn * BN + wn * 128;
#pragma unroll
    for (int n = 0; n < 8; ++n) {
        const int col = col0 + n * 16 + lr;
        const float bc = bias[col];
#pragma unroll
        for (int m = 0; m < 8; ++m) {
#pragma unroll
            for (int j = 0; j < 4; ++j) {
                const int row = row0 + m * 16 + kq * 4 + j;
                float y = acc[m][n][j] * wscale + bc;
                float q = rintf(y / oscale);          // round-half-even, matches jnp.round
                q = fminf(fmaxf(q, -128.0f), 127.0f);
                C[(size_t)row * O_FEAT + col] = q * oscale;
            }
        }
    }
}

extern "C" void kernel_launch(void* const* d_in, const int* in_sizes, int n_in,
                              void* d_out, int out_size, void* d_ws, size_t ws_size,
                              hipStream_t stream) {
    const float* x        = (const float*)d_in[0];  // [8192,4096] fp32
    const float* wq       = (const float*)d_in[1];  // [4096,4096] fp32 (int8 values)
    const float* bias     = (const float*)d_in[2];  // [4096]
    const float* w_scale  = (const float*)d_in[3];  // scalar
    const float* out_scale= (const float*)d_in[4];  // scalar
    const int*   mask     = (const int*)d_in[5];    // [4096,1024] int32
    float* out = (float*)d_out;

    _Float16* xf = (_Float16*)d_ws;                                        // 64 MiB
    _Float16* wf = (_Float16*)((char*)d_ws + (size_t)M_TOK * K_FEAT * 2);  // +32 MiB

    // fused cvt: 16384 x-blocks + 8192 w-blocks
    cvt_kernel<<<NXBLK + (O_FEAT * K_FEAT / 8 / 256), 256, 0, stream>>>(x, wq, mask, xf, wf);

    // (8192/256) x (4096/256) = 32*16 = 512 blocks, 256 threads (4 waves)
    gemm_kernel<<<dim3((M_TOK / BM) * (O_FEAT / BN)), 256, 0, stream>>>(
        xf, wf, bias, w_scale, out_scale, out);
}